// Round 12
// baseline (526.391 us; speedup 1.0000x reference)
//
#include <hip/hip_runtime.h>
#include <math.h>

#define MINN 1e-15f
#define ONE_EPS 0.99999f   // 1 - 1e-5 (artanh clamp)

// lgkm-only barrier: orders LDS writes across waves WITHOUT draining vmcnt
// (HIP __syncthreads drains vmcnt(0), killing cross-iteration global
// prefetch). Single asm block so no compiler reordering window.
#define BARSYNC() asm volatile("s_waitcnt lgkmcnt(0)\n\ts_barrier" ::: "memory")

__device__ __forceinline__ float clampart(float x) {
  return fminf(fmaxf(x, -1.0f + 1e-5f), 1.0f - 1e-5f);
}
__device__ __forceinline__ float redsum(float x) {
  #pragma unroll
  for (int m = 32; m; m >>= 1) x += __shfl_xor(x, m);
  return x;
}
// 5-level butterfly within each 32-lane half
__device__ __forceinline__ float redsum32(float x) {
  #pragma unroll
  for (int m = 16; m; m >>= 1) x += __shfl_xor(x, m);
  return x;
}
__device__ __forceinline__ float frcp(float x) { return __builtin_amdgcn_rcpf(x); }
__device__ __forceinline__ float frsq(float x) { return __builtin_amdgcn_rsqf(x); }
__device__ __forceinline__ float fexp2(float x) { return __builtin_amdgcn_exp2f(x); }
__device__ __forceinline__ float flog2(float x) { return __builtin_amdgcn_logf(x); }
__device__ __forceinline__ float ftanh(float x) {
  float e = fexp2(x * 2.88539008f);
  return 1.0f - 2.0f * frcp(e + 1.0f);
}
__device__ __forceinline__ float fatanh(float x) {
  return 0.34657359f * flog2((1.0f + x) * frcp(1.0f - x));
}
__device__ __forceinline__ float fsig(float x) {
  return frcp(1.0f + fexp2(-1.44269504f * x));
}
#define DOT4(a, b) ((a).x*(b).x + (a).y*(b).y + (a).z*(b).z + (a).w*(b).w)

// ---- bf16 split helpers (x = hi + lo, each bf16; rel err ~2^-18) ----------
__device__ __forceinline__ unsigned bfh(float x) {
  unsigned u = __float_as_uint(x);
  return (u + 0x7FFFu + ((u >> 16) & 1u)) >> 16;    // RNE to bf16 bits
}
__device__ __forceinline__ void splitpack(float4 q0, float4 q1,
                                          uint4& hi, uint4& lo) {
  unsigned h0=bfh(q0.x),h1=bfh(q0.y),h2=bfh(q0.z),h3=bfh(q0.w);
  unsigned h4=bfh(q1.x),h5=bfh(q1.y),h6=bfh(q1.z),h7=bfh(q1.w);
  float r0=q0.x-__uint_as_float(h0<<16), r1=q0.y-__uint_as_float(h1<<16);
  float r2=q0.z-__uint_as_float(h2<<16), r3=q0.w-__uint_as_float(h3<<16);
  float r4=q1.x-__uint_as_float(h4<<16), r5=q1.y-__uint_as_float(h5<<16);
  float r6=q1.z-__uint_as_float(h6<<16), r7=q1.w-__uint_as_float(h7<<16);
  hi = make_uint4(h0|(h1<<16), h2|(h3<<16), h4|(h5<<16), h6|(h7<<16));
  lo = make_uint4(bfh(r0)|(bfh(r1)<<16), bfh(r2)|(bfh(r3)<<16),
                  bfh(r4)|(bfh(r5)<<16), bfh(r6)|(bfh(r7)<<16));
}
typedef __attribute__((ext_vector_type(8))) short bf16x8;
typedef __attribute__((ext_vector_type(4))) float f32x4;
__device__ __forceinline__ bf16x8 asfrag(uint4 u) {
  union { uint4 u; bf16x8 f; } c; c.u = u; return c.f;
}

// -------- Kernel B0: U matrices -> bf16 hi/lo fragment-linear layout -------
__global__ __launch_bounds__(256) void k_convB(const float* __restrict__ uz,
    const float* __restrict__ ur, const float* __restrict__ uh,
    uint4* __restrict__ Bh, uint4* __restrict__ Bl) {
  int tid = threadIdx.x;
  int l = tid & 63;
  int s = blockIdx.x * 4 + (tid >> 6);     // 0..575
  int kt = s / 24, nt = s % 24;
  int n = nt * 16 + (l & 15);
  const float* U = (n < 128) ? uz : (n < 256 ? ur : uh);
  int i = n & 127;
  int k = kt * 32 + (l >> 4) * 8;
  float4 q0 = *reinterpret_cast<const float4*>(U + (size_t)i * 768 + k);
  float4 q1 = *reinterpret_cast<const float4*>(U + (size_t)i * 768 + k + 4);
  uint4 hi, lo;
  splitpack(q0, q1, hi, lo);
  Bh[(size_t)(kt * 24 + nt) * 64 + l] = hi;
  Bl[(size_t)(kt * 24 + nt) * 64 + l] = lo;
}

// -------- Kernel B: fused MFMA GEMM + expmap0 stats + mobius_matvec NL -----
// B staged per-kt in double-buffered LDS; lgkm-only barriers keep the next
// tile's global loads in flight across the barrier.
__global__ __launch_bounds__(256, 1) void k_gemm_fused(
    const float* __restrict__ A, const uint4* __restrict__ Bh,
    const uint4* __restrict__ Bl,
    const float* __restrict__ bzp, const float* __restrict__ brp,
    const float* __restrict__ bhp,
    float* __restrict__ mx, float* __restrict__ yn, float* __restrict__ ub) {
  __shared__ uint4 bstage[2][3072];        // [buf][Bh:0..1535 | Bl:1536..3071]
  int tid = threadIdx.x;
  int l = tid & 63;
  int wv = tid >> 6;                       // wave 0..3
  int wid = blockIdx.x * 4 + wv;           // 0..1023
  int mt0 = wid * 2;
  int mrow = l & 15;
  int koff = (l >> 4) * 8;
  int sbase = wv * 384 + l;                // staging slot base (6 chunks of 64)

  f32x4 acc[2][24];
  #pragma unroll
  for (int m = 0; m < 2; ++m)
    #pragma unroll
    for (int n = 0; n < 24; ++n) acc[m][n] = (f32x4){0.f, 0.f, 0.f, 0.f};
  float ssA0 = 0.f, ssA1 = 0.f;

  // prologue: stage kt=0 into buf 0
  {
    const uint4* sH = Bh;                  // kt=0
    const uint4* sL = Bl;
    #pragma unroll
    for (int j = 0; j < 6; ++j) {
      bstage[0][sbase + j * 64]        = sH[sbase + j * 64];
      bstage[0][1536 + sbase + j * 64] = sL[sbase + j * 64];
    }
  }
  BARSYNC();

  #pragma unroll 1
  for (int kt = 0; kt < 24; ++kt) {
    int cb = kt & 1;
    // stage kt+1 into the other buffer (loads overlap this kt's MFMA)
    if (kt + 1 < 24) {
      const uint4* sH = Bh + (size_t)(kt + 1) * 1536;
      const uint4* sL = Bl + (size_t)(kt + 1) * 1536;
      #pragma unroll
      for (int j = 0; j < 6; ++j) {
        bstage[cb ^ 1][sbase + j * 64]        = sH[sbase + j * 64];
        bstage[cb ^ 1][1536 + sbase + j * 64] = sL[sbase + j * 64];
      }
    }
    const float* a0p = A + (size_t)(mt0 * 16 + mrow) * 768 + kt * 32 + koff;
    const float* a1p = a0p + 16 * 768;
    float4 q0 = *reinterpret_cast<const float4*>(a0p);
    float4 q1 = *reinterpret_cast<const float4*>(a0p + 4);
    float4 q2 = *reinterpret_cast<const float4*>(a1p);
    float4 q3 = *reinterpret_cast<const float4*>(a1p + 4);
    ssA0 += DOT4(q0, q0) + DOT4(q1, q1);
    ssA1 += DOT4(q2, q2) + DOT4(q3, q3);
    uint4 ah0u, al0u, ah1u, al1u;
    splitpack(q0, q1, ah0u, al0u);
    splitpack(q2, q3, ah1u, al1u);
    bf16x8 ah0 = asfrag(ah0u), al0 = asfrag(al0u);
    bf16x8 ah1 = asfrag(ah1u), al1 = asfrag(al1u);
    const uint4* bhp4 = &bstage[cb][l];
    const uint4* blp4 = &bstage[cb][1536 + l];
    #pragma unroll
    for (int nt = 0; nt < 24; ++nt) {
      bf16x8 bh = asfrag(bhp4[nt * 64]);
      bf16x8 bl = asfrag(blp4[nt * 64]);
      acc[0][nt] = __builtin_amdgcn_mfma_f32_16x16x32_bf16(ah0, bh, acc[0][nt], 0, 0, 0);
      acc[0][nt] = __builtin_amdgcn_mfma_f32_16x16x32_bf16(ah0, bl, acc[0][nt], 0, 0, 0);
      acc[0][nt] = __builtin_amdgcn_mfma_f32_16x16x32_bf16(al0, bh, acc[0][nt], 0, 0, 0);
      acc[0][nt] = __builtin_amdgcn_mfma_f32_16x16x32_bf16(al0, bl, acc[0][nt], 0, 0, 0);
      acc[1][nt] = __builtin_amdgcn_mfma_f32_16x16x32_bf16(ah1, bh, acc[1][nt], 0, 0, 0);
      acc[1][nt] = __builtin_amdgcn_mfma_f32_16x16x32_bf16(ah1, bl, acc[1][nt], 0, 0, 0);
      acc[1][nt] = __builtin_amdgcn_mfma_f32_16x16x32_bf16(al1, bh, acc[1][nt], 0, 0, 0);
      acc[1][nt] = __builtin_amdgcn_mfma_f32_16x16x32_bf16(al1, bl, acc[1][nt], 0, 0, 0);
    }
    BARSYNC();   // staging visible + all waves done reading buf cb
  }
  // ---- seq row stats (A layout: lane covers koff-quarter of row mrow) ----
  ssA0 += __shfl_xor(ssA0, 16); ssA0 += __shfl_xor(ssA0, 32);
  ssA1 += __shfl_xor(ssA1, 16); ssA1 += __shfl_xor(ssA1, 32);
  float aA[2], rxA[2];
  {
    float un0 = sqrtf(ssA0), unc0 = fmaxf(un0, MINN);
    float a0 = tanhf(unc0) / unc0;
    float xn0 = fmaxf(a0 * un0, MINN);
    aA[0] = a0; rxA[0] = atanhf(clampart(xn0)) / xn0;
    float un1 = sqrtf(ssA1), unc1 = fmaxf(un1, MINN);
    float a1 = tanhf(unc1) / unc1;
    float xn1 = fmaxf(a1 * un1, MINN);
    aA[1] = a1; rxA[1] = atanhf(clampart(xn1)) / xn1;
  }
  // ---- remap stats to C-layout rows (row = r0 + j) ----
  int r0 = (l >> 4) * 4;
  float aC[2][4], rxC[2][4];
  #pragma unroll
  for (int m = 0; m < 2; ++m)
    #pragma unroll
    for (int j = 0; j < 4; ++j) {
      aC[m][j]  = __shfl(aA[m],  r0 + j);
      rxC[m][j] = __shfl(rxA[m], r0 + j);
    }
  // ---- bias values for ub dots: b_g[col], col = nt*16 + mrow ----
  float bv0[8], bv1[8], bv2[8];
  #pragma unroll
  for (int i = 0; i < 8; ++i) {
    bv0[i] = bzp[i * 16 + mrow];
    bv1[i] = brp[i * 16 + mrow];
    bv2[i] = bhp[i * 16 + mrow];
  }
#define GATE_EPI(m, g, bvarr)                                                 \
  {                                                                           \
    float ss0=0.f,ss1=0.f,ss2=0.f,ss3=0.f,sb0=0.f,sb1=0.f,sb2=0.f,sb3=0.f;    \
    _Pragma("unroll")                                                         \
    for (int ntg = 0; ntg < 8; ++ntg) {                                       \
      f32x4 v = acc[m][(g)*8 + ntg];                                          \
      float bb = bvarr[ntg];                                                  \
      ss0 += v[0]*v[0]; sb0 += v[0]*bb;                                       \
      ss1 += v[1]*v[1]; sb1 += v[1]*bb;                                       \
      ss2 += v[2]*v[2]; sb2 += v[2]*bb;                                       \
      ss3 += v[3]*v[3]; sb3 += v[3]*bb;                                       \
    }                                                                         \
    _Pragma("unroll")                                                         \
    for (int mk = 1; mk <= 8; mk <<= 1) {                                     \
      ss0 += __shfl_xor(ss0, mk); sb0 += __shfl_xor(sb0, mk);                 \
      ss1 += __shfl_xor(ss1, mk); sb1 += __shfl_xor(sb1, mk);                 \
      ss2 += __shfl_xor(ss2, mk); sb2 += __shfl_xor(sb2, mk);                 \
      ss3 += __shfl_xor(ss3, mk); sb3 += __shfl_xor(sb3, mk);                 \
    }                                                                         \
    float ssv[4] = {ss0, ss1, ss2, ss3};                                      \
    float sbv[4] = {sb0, sb1, sb2, sb3};                                      \
    float scale[4];                                                           \
    _Pragma("unroll")                                                         \
    for (int j = 0; j < 4; ++j) {                                             \
      float mxn = fmaxf(aC[m][j] * sqrtf(ssv[j]), MINN);                      \
      float tt = tanhf(mxn * rxC[m][j]);                                      \
      float sc = tt / mxn;                                                    \
      scale[j] = aC[m][j] * sc;                                               \
      if (mrow == 0) {                                                        \
        size_t row = (size_t)(mt0 + (m)) * 16 + r0 + j;                       \
        yn[row * 4 + (g)] = tt;                                               \
        ub[row * 4 + (g)] = scale[j] * sbv[j];                                \
      }                                                                       \
    }                                                                         \
    _Pragma("unroll")                                                         \
    for (int ntg = 0; ntg < 8; ++ntg) {                                       \
      int col = ((g)*8 + ntg) * 16 + mrow;                                    \
      f32x4 v = acc[m][(g)*8 + ntg];                                          \
      size_t rbase = (size_t)(mt0 + (m)) * 16 + r0;                           \
      _Pragma("unroll")                                                       \
      for (int j = 0; j < 4; ++j)                                             \
        mx[(rbase + j) * 384 + col] = v[j] * scale[j];                        \
    }                                                                         \
  }
  GATE_EPI(0, 0, bv0) GATE_EPI(0, 1, bv1) GATE_EPI(0, 2, bv2)
  GATE_EPI(1, 0, bv0) GATE_EPI(1, 1, bv1) GATE_EPI(1, 2, bv2)
#undef GATE_EPI
}

// ---------------- Kernel C: hyperbolic GRU scan, 4 waves per chain --------
// Weights in VGPRs; full input prefetch; rsq-folded chain; split-half
// reductions; lgkm-only barriers (global prefetch stays in flight across
// all 5 per-step barriers -> waits land at next-iteration first use).
__global__ __launch_bounds__(256, 1) void k_scan(
    const float* __restrict__ ux, const float* __restrict__ yn,
    const float* __restrict__ ub,
    const float* __restrict__ wz, const float* __restrict__ wr, const float* __restrict__ wh,
    const float* __restrict__ bzp, const float* __restrict__ brp, const float* __restrict__ bhp,
    const float* __restrict__ mask1, const float* __restrict__ mask2,
    float* __restrict__ uarr, float* __restrict__ varr) {
  __shared__ __align__(16) float hs[128];
  __shared__ __align__(16) float ps[128];
  __shared__ __align__(16) float part[72];
  float4* hs4   = (float4*)hs;
  float4* ps4   = (float4*)ps;
  float4* part4 = (float4*)part;

  int b = blockIdx.x;
  int tid = threadIdx.x;
  int w = tid >> 6;          // wave 0..3
  int l = tid & 63;          // lane
  int l31 = l & 31;
  int kh = l >> 5;           // k-half 0/1 (also reduction-subset selector)
  int o = w * 32 + l31;      // owned output/elem index

  const float4* wzg = (const float4*)wz;
  const float4* wrg = (const float4*)wr;
  const float4* whg = (const float4*)wh;
  float4 wzr[16], wrr[16], whr[16];
  #pragma unroll
  for (int i = 0; i < 16; ++i) {
    wzr[i] = wzg[o * 32 + kh * 16 + i];
    wrr[i] = wrg[o * 32 + kh * 16 + i];
    whr[i] = whg[o * 32 + kh * 16 + i];
  }

  float bzv = bzp[o], brv = brp[o], bhv = bhp[o];
  {
    float v0 = redsum32(bzv * bzv);
    float v1 = redsum32(brv * brv);
    float v2 = redsum32(bhv * bhv);
    if (l == 0) { part[15*4 + w] = v0; part[16*4 + w] = v1; part[17*4 + w] = v2; }
  }
  BARSYNC();
  float b2z, b2r, b2h;
  { float4 q;
    q = part4[15]; b2z = q.x + q.y + q.z + q.w;
    q = part4[16]; b2r = q.x + q.y + q.z + q.w;
    q = part4[17]; b2h = q.x + q.y + q.z + q.w; }

  float h = 0.f, hn2 = 0.f, au = 0.f, av = 0.f;
  const float*  uxb  = ux + (size_t)b * 128 * 384;
  const float4* ynb4 = (const float4*)yn + (size_t)b * 128;
  const float4* ubb4 = (const float4*)ub + (size_t)b * 128;
  const float*  m1p  = mask1 + b * 128;
  const float*  m2p  = mask2 + b * 128;

  // prefetch t=0 inputs
  float cuz = uxb[o], cur = uxb[128 + o], cuh = uxb[256 + o];
  float4 cyn = ynb4[0];
  float4 cub = ubb4[0];
  float cm1 = m1p[0], cm2 = m2p[0];

  #pragma unroll 1
  for (int t = 0; t < 128; ++t) {
    hs[o] = h;                            // both halves write identical value
    BARSYNC();                            // (1) h visible
    // issue ALL t+1 prefetches (stay in flight across barriers now)
    int tn = (t < 127) ? t + 1 : 127;
    const float* uxn = uxb + tn * 384;
    float nuz = uxn[o], nur = uxn[128 + o], nuh = uxn[256 + o];
    float4 nyn = ynb4[tn];
    float4 nub = ubb4[tn];
    float nm1 = m1p[tn], nm2 = m2p[tn];
    float uz = cuz, ur = cur, uh = cuh;
    float ynz = cyn.x, ynr = cyn.y, ynh = cyn.z;
    float ubz = cub.x, ubr = cub.y, ubh = cub.z;
    float m1 = cm1, m2 = cm2;

    // wave-uniform pre-chain
    float rqh  = frsq(fmaxf(hn2, 1e-30f));
    float xnh  = fmaxf(hn2, 1e-30f) * rqh;
    float arth = fatanh(fminf(xnh, ONE_EPS));
    float axr  = arth * rqh;

    // ---- z/r matvec: register weights x LDS-broadcast h ----
    float mzp = 0.f, mrp = 0.f;
    #pragma unroll
    for (int i = 0; i < 16; ++i) {
      float4 hv = hs4[kh * 16 + i];
      mzp += DOT4(wzr[i], hv);
      mrp += DOT4(wrr[i], hv);
    }
    float mz = mzp + __shfl_xor(mzp, 32);
    float mr = mrp + __shfl_xor(mrp, 32);

    // ---- window A: 6 reductions, split 3/3 across halves ----
    {
      float v0 = kh ? mr * mr  : mz * mz;
      float v1 = kh ? mr * ur  : mz * uz;
      float v2 = kh ? mr * brv : mz * bzv;
      v0 = redsum32(v0); v1 = redsum32(v1); v2 = redsum32(v2);
      if (l31 == 0) {
        int base = kh * 3;
        part[(base + 0) * 4 + w] = v0;
        part[(base + 1) * 4 + w] = v1;
        part[(base + 2) * 4 + w] = v2;
      }
    }
    BARSYNC();                            // (2) window A partials
    float sMz2, sMzUz, sMzBz, sMr2, sMrUr, sMrBr;
    { float4 q;
      q = part4[0]; sMz2  = q.x + q.y + q.z + q.w;
      q = part4[1]; sMzUz = q.x + q.y + q.z + q.w;
      q = part4[2]; sMzBz = q.x + q.y + q.z + q.w;
      q = part4[3]; sMr2  = q.x + q.y + q.z + q.w;
      q = part4[4]; sMrUr = q.x + q.y + q.z + q.w;
      q = part4[5]; sMrBr = q.x + q.y + q.z + q.w; }

    // ---- z chain (rsq-folded) ----
    float rqz = frsq(fmaxf(sMz2, 1e-30f));
    float mzn = fmaxf(sMz2, 1e-30f) * rqz;
    float tz  = ftanh(mzn * axr);
    float szs = tz * rqz;
    float xyz = szs * sMzUz;
    float y2z = ynz * ynz, x2z = tz * tz;
    float c1z = 1.f + 2.f * xyz + y2z, c2z = 1.f - x2z;
    float idnz = frcp(fmaxf(1.f + 2.f * xyz + x2z * y2z, MINN));
    float az  = (c1z * szs * mz + c2z * uz) * idnz;
    float az2 = fmaxf(idnz * idnz * (c1z * c1z * x2z + 2.f * c1z * c2z * xyz + c2z * c2z * y2z), 0.f);
    float azb = idnz * (c1z * szs * sMzBz + c2z * ubz);
    float c1zb = 1.f + 2.f * azb + b2z, c2zb = 1.f - az2;
    float idnzb = frcp(fmaxf(1.f + 2.f * azb + az2 * b2z, MINN));
    float cz = (c1zb * az + c2zb * bzv) * idnzb;
    float cn2z = fmaxf(idnzb * idnzb * (c1zb * c1zb * az2 + 2.f * c1zb * c2zb * azb + c2zb * c2zb * b2z), 0.f);
    float rqcz = frsq(fmaxf(cn2z, 1e-30f));
    float cnz = fmaxf(cn2z, 1e-30f) * rqcz;
    float lsz = fatanh(fminf(cnz, ONE_EPS)) * rqcz;
    float zg = fsig(lsz * cz);

    // ---- r chain ----
    float rqr = frsq(fmaxf(sMr2, 1e-30f));
    float mrn = fmaxf(sMr2, 1e-30f) * rqr;
    float trr = ftanh(mrn * axr);
    float srs = trr * rqr;
    float xyr = srs * sMrUr;
    float y2r = ynr * ynr, x2r = trr * trr;
    float c1r = 1.f + 2.f * xyr + y2r, c2r = 1.f - x2r;
    float idnr = frcp(fmaxf(1.f + 2.f * xyr + x2r * y2r, MINN));
    float ar  = (c1r * srs * mr + c2r * ur) * idnr;
    float ar2 = fmaxf(idnr * idnr * (c1r * c1r * x2r + 2.f * c1r * c2r * xyr + c2r * c2r * y2r), 0.f);
    float arb = idnr * (c1r * srs * sMrBr + c2r * ubr);
    float c1rb = 1.f + 2.f * arb + b2r, c2rb = 1.f - ar2;
    float idnrb = frcp(fmaxf(1.f + 2.f * arb + ar2 * b2r, MINN));
    float cr = (c1rb * ar + c2rb * brv) * idnrb;
    float cn2r = fmaxf(idnrb * idnrb * (c1rb * c1rb * ar2 + 2.f * c1rb * c2rb * arb + c2rb * c2rb * b2r), 0.f);
    float rqcr = frsq(fmaxf(cn2r, 1e-30f));
    float cnr = fmaxf(cn2r, 1e-30f) * rqcr;
    float lsr = fatanh(fminf(cnr, ONE_EPS)) * rqcr;
    float rg = fsig(lsr * cr);

    // ---- rh = h o r (unscaled p) ----
    float p = h * rg;
    ps[o] = p;                            // both halves, identical value
    BARSYNC();                            // (3) p visible

    // ---- h matvec from regs x ps broadcast ----
    float mhp = 0.f;
    #pragma unroll
    for (int i = 0; i < 16; ++i) {
      float4 pv = ps4[kh * 16 + i];
      mhp += DOT4(whr[i], pv);
    }
    float mh = mhp + __shfl_xor(mhp, 32);

    // ---- window B: 7 reductions, split 4/3 across halves ----
    {
      float v0 = kh ? (h * mh)  : (p * p);
      float v1 = kh ? (h * uh)  : (mh * mh);
      float v2 = kh ? (h * bhv) : (mh * uh);
      float v3 = kh ? 0.f       : (mh * bhv);
      v0 = redsum32(v0); v1 = redsum32(v1); v2 = redsum32(v2); v3 = redsum32(v3);
      if (l31 == 0) {
        if (kh) {
          part[10*4 + w] = v0; part[11*4 + w] = v1; part[12*4 + w] = v2;
        } else {
          part[6*4 + w] = v0; part[7*4 + w] = v1;
          part[8*4 + w] = v2; part[9*4 + w] = v3;
        }
      }
    }
    BARSYNC();                            // (4) window B partials
    float pn2, sMh2r, sMhUhr, sMhBhr, sHMhr, sHUh, sHBh;
    { float4 q;
      q = part4[6];  pn2    = q.x + q.y + q.z + q.w;
      q = part4[7];  sMh2r  = q.x + q.y + q.z + q.w;
      q = part4[8];  sMhUhr = q.x + q.y + q.z + q.w;
      q = part4[9];  sMhBhr = q.x + q.y + q.z + q.w;
      q = part4[10]; sHMhr  = q.x + q.y + q.z + q.w;
      q = part4[11]; sHUh   = q.x + q.y + q.z + q.w;
      q = part4[12]; sHBh   = q.x + q.y + q.z + q.w; }

    // ---- rh scaling + h~ chain (rsq-folded, srt folded) ----
    float rqp = frsq(fmaxf(pn2, 1e-30f));
    float pn  = fmaxf(pn2, 1e-30f) * rqp;
    float trh = ftanh(pn * axr);
    float srt = trh * rqp;
    float xnp  = fmaxf(trh, MINN);
    float artp = fatanh(fminf(xnp, ONE_EPS));
    float sqh  = fmaxf(sMh2r, 1e-30f) * frsq(fmaxf(sMh2r, 1e-30f));  // sqrt
    float mhn  = fmaxf(srt * sqh, MINN);
    float th   = ftanh(mhn * artp * frcp(xnp));
    float g    = th * frcp(mhn) * srt;
    float xyh  = g * sMhUhr;
    float y2h = ynh * ynh, x2h = th * th;
    float c1h = 1.f + 2.f * xyh + y2h, c2h = 1.f - x2h;
    float idnh = frcp(fmaxf(1.f + 2.f * xyh + x2h * y2h, MINN));
    float ah  = (c1h * g * mh + c2h * uh) * idnh;
    float ah2 = fmaxf(idnh * idnh * (c1h * c1h * x2h + 2.f * c1h * c2h * xyh + c2h * c2h * y2h), 0.f);
    float ahb = idnh * (c1h * g * sMhBhr + c2h * ubh);
    float hah = idnh * (c1h * g * sHMhr + c2h * sHUh);
    float c1hb = 1.f + 2.f * ahb + b2h, c2hb = 1.f - ah2;
    float idnhb = frcp(fmaxf(1.f + 2.f * ahb + ah2 * b2h, MINN));
    float ct  = (c1hb * ah + c2hb * bhv) * idnhb;
    float ct2 = fmaxf(idnhb * idnhb * (c1hb * c1hb * ah2 + 2.f * c1hb * c2hb * ahb + c2hb * c2hb * b2h), 0.f);
    float hct = idnhb * (c1hb * hah + c2hb * sHBh);

    // ---- delta = mobius_add(-h, h_tilde) ----
    float c1d = 1.f - 2.f * hct + ct2, c2d = 1.f - hn2;
    float idnd = frcp(fmaxf(1.f - 2.f * hct + hn2 * ct2, MINN));
    float dl = (c2d * ct - c1d * h) * idnd;
    float dn2 = fmaxf(idnd * idnd * (c1d * c1d * hn2 - 2.f * c1d * c2d * hct + c2d * c2d * ct2), 0.f);
    float wv = dl * zg;

    // ---- window C: 2 reductions, split 1/1 across halves ----
    {
      float vC = kh ? (h * wv) : (wv * wv);
      vC = redsum32(vC);
      if (l31 == 0) part[(13 + kh) * 4 + w] = vC;
    }
    BARSYNC();                            // (5) window C partials
    float wn2, hw;
    { float4 q;
      q = part4[13]; wn2 = q.x + q.y + q.z + q.w;
      q = part4[14]; hw  = q.x + q.y + q.z + q.w; }

    float rqd = frsq(fmaxf(dn2, 1e-30f));
    float dnv = fmaxf(dn2, 1e-30f) * rqd;
    float rqw = frsq(fmaxf(wn2, 1e-30f));
    float wnv = fmaxf(wn2, 1e-30f) * rqw;
    float tdd = ftanh(wnv * rqd * fatanh(fminf(dnv, ONE_EPS)));
    float szd = tdd * rqw;
    float zd = wv * szd;
    float hzd = hw * szd;
    float t2v = tdd * tdd;
    float c1f = 1.f + 2.f * hzd + t2v, c2f = 1.f - hn2;
    float idnf = frcp(fmaxf(1.f + 2.f * hzd + hn2 * t2v, MINN));
    float nh = (c1f * h + c2f * zd) * idnf;
    hn2 = fmaxf(idnf * idnf * (c1f * c1f * hn2 + 2.f * c1f * c2f * hzd + c2f * c2f * t2v), 0.f);
    h = nh;
    au += m1 * h; av += m2 * h;
    cuz = nuz; cur = nur; cuh = nuh;
    cyn = nyn; cub = nub; cm1 = nm1; cm2 = nm2;
  }
  if (l < 32) {
    uarr[b * 128 + o] = au;
    varr[b * 128 + o] = av;
  }
}

// ---------------- Kernel D: dist + mobius FF + hyperbolic MLR, 1 wave/b ----
__global__ __launch_bounds__(64) void k_final(
    const float* __restrict__ uarr, const float* __restrict__ varr,
    const float* __restrict__ wfu, const float* __restrict__ wfv,
    const float* __restrict__ bff, const float* __restrict__ bffd,
    const float* __restrict__ wfc, const float* __restrict__ pmlr,
    const float* __restrict__ amlr, const int* __restrict__ cids,
    const float* __restrict__ csemb, float* __restrict__ out) {
  int b = blockIdx.x;
  int l = threadIdx.x;
  __shared__ float us[128], vs[128], cbuf[64];
  float q0 = uarr[b * 128 + l], q1 = uarr[b * 128 + 64 + l];
  float r0 = varr[b * 128 + l], r1 = varr[b * 128 + 64 + l];
  us[l] = q0; us[l + 64] = q1; vs[l] = r0; vs[l + 64] = r1;
  __syncthreads();
  float u2 = redsum(q0 * q0 + q1 * q1);
  float v2 = redsum(r0 * r0 + r1 * r1);
  float uv = redsum(q0 * r0 + q1 * r1);
  float dsq;
  { float x2 = u2, y2 = v2, xy = -uv;
    float c1 = 1.f + 2.f * xy + y2, c2 = 1.f - x2;
    float idn = 1.f / fmaxf(1.f + 2.f * xy + x2 * y2, MINN);
    float d0 = (c1 * (-q0) + c2 * r0) * idn, d1 = (c1 * (-q1) + c2 * r1) * idn;
    float dn2 = redsum(d0 * d0 + d1 * d1);
    dsq = 2.f * atanhf(clampart(sqrtf(dn2))); }
  float mxu = 0.f, mxv = 0.f;
  #pragma unroll 4
  for (int jc = 0; jc < 128; jc += 4) {
    float4 uu = *reinterpret_cast<const float4*>(&us[jc]);
    float4 vv = *reinterpret_cast<const float4*>(&vs[jc]);
    float4 wu4 = *reinterpret_cast<const float4*>(wfu + (size_t)l * 128 + jc);
    float4 wv4 = *reinterpret_cast<const float4*>(wfv + (size_t)l * 128 + jc);
    mxu += DOT4(wu4, uu); mxv += DOT4(wv4, vv);
  }
  float xnu = fmaxf(sqrtf(u2), MINN);
  float xnv = fmaxf(sqrtf(v2), MINN);
  float mun = fmaxf(sqrtf(redsum(mxu * mxu)), MINN);
  float mvn = fmaxf(sqrtf(redsum(mxv * mxv)), MINN);
  float tu = tanhf(mun / xnu * atanhf(clampart(xnu)));
  float tv = tanhf(mvn / xnv * atanhf(clampart(xnv)));
  float fu = mxu * (tu / mun), fv = mxv * (tv / mvn);
  float o1;
  { float x2 = tu * tu, y2 = tv * tv, xy = redsum(fu * fv);
    float c1 = 1.f + 2.f * xy + y2, c2 = 1.f - x2;
    float idn = 1.f / fmaxf(1.f + 2.f * xy + x2 * y2, MINN);
    o1 = (c1 * fu + c2 * fv) * idn; }
  float bffl = bff[l];
  float bf2 = redsum(bffl * bffl);
  float o2;
  { float x2 = redsum(o1 * o1), y2 = bf2, xy = redsum(o1 * bffl);
    float c1 = 1.f + 2.f * xy + y2, c2 = 1.f - x2;
    float idn = 1.f / fmaxf(1.f + 2.f * xy + x2 * y2, MINN);
    o2 = (c1 * o1 + c2 * bffl) * idn; }
  float bdl = bffd[l];
  float bdn = fmaxf(sqrtf(redsum(bdl * bdl)), MINN);
  float tsm = tanhf(dsq * atanhf(clampart(bdn)));
  float sm = bdl * (tsm / bdn);
  float o3;
  { float x2 = redsum(o2 * o2), y2 = tsm * tsm, xy = redsum(o2 * sm);
    float c1 = 1.f + 2.f * xy + y2, c2 = 1.f - x2;
    float idn = 1.f / fmaxf(1.f + 2.f * xy + x2 * y2, MINN);
    o3 = (c1 * o2 + c2 * sm) * idn; }
  int cid = cids[b];
  float ce = csemb[(size_t)cid * 64 + l];
  cbuf[l] = ce;
  __syncthreads();
  float ce2 = redsum(ce * ce);
  float mxc = 0.f;
  #pragma unroll 4
  for (int jc = 0; jc < 64; jc += 4) {
    float4 cc = *reinterpret_cast<const float4*>(&cbuf[jc]);
    float4 wc4 = *reinterpret_cast<const float4*>(wfc + (size_t)l * 64 + jc);
    mxc += DOT4(wc4, cc);
  }
  float xnc = fmaxf(sqrtf(ce2), MINN);
  float mcn = fmaxf(sqrtf(redsum(mxc * mxc)), MINN);
  float tc = tanhf(mcn / xnc * atanhf(clampart(xnc)));
  float fc = mxc * (tc / mcn);
  float o4;
  { float x2 = redsum(o3 * o3), y2 = tc * tc, xy = redsum(o3 * fc);
    float c1 = 1.f + 2.f * xy + y2, c2 = 1.f - x2;
    float idn = 1.f / fmaxf(1.f + 2.f * xy + x2 * y2, MINN);
    o4 = (c1 * o3 + c2 * fc) * idn; }
  float on = fmaxf(sqrtf(redsum(o4 * o4)), MINN);
  float lo = o4 * (atanhf(clampart(on)) / on);
  float un = fmaxf(sqrtf(redsum(lo * lo)), MINN);
  float eo = lo * (tanhf(un) / un);
  float eo2 = redsum(eo * eo);
  for (int c = 0; c < 4; ++c) {
    float pc = pmlr[c * 64 + l];
    float ac = amlr[c * 64 + l];
    float p2 = redsum(pc * pc);
    float pe = redsum(pc * eo);
    float x2 = p2, y2 = eo2, xy = -pe;
    float c1 = 1.f + 2.f * xy + y2, c2 = 1.f - x2;
    float idn = 1.f / fmaxf(1.f + 2.f * xy + x2 * y2, MINN);
    float mp = (c1 * (-pc) + c2 * eo) * idn;
    float mp2 = redsum(mp * mp);
    float lam = 2.f / (1.f - mp2);
    float na = sqrtf(redsum(ac * ac));
    float au = ac / fmaxf(na, 1e-12f);
    float pda = redsum(mp * au);
    if (l == 0) out[b * 4 + c] = 2.f * na * asinhf(pda * lam);
  }
}

extern "C" void kernel_launch(void* const* d_in, const int* in_sizes, int n_in,
                              void* d_out, int out_size, void* d_ws, size_t ws_size,
                              hipStream_t stream) {
  const float* seq   = (const float*)d_in[0];
  const float* mask1 = (const float*)d_in[1];
  const float* mask2 = (const float*)d_in[2];
  const int*   cids  = (const int*)d_in[3];
  const float* csemb = (const float*)d_in[4];
  const float* wz  = (const float*)d_in[5];
  const float* wr  = (const float*)d_in[6];
  const float* wh  = (const float*)d_in[7];
  const float* uz  = (const float*)d_in[8];
  const float* ur  = (const float*)d_in[9];
  const float* uh  = (const float*)d_in[10];
  const float* bz  = (const float*)d_in[11];
  const float* br  = (const float*)d_in[12];
  const float* bh  = (const float*)d_in[13];
  const float* wfu = (const float*)d_in[14];
  const float* wfv = (const float*)d_in[15];
  const float* bff = (const float*)d_in[16];
  const float* bffd= (const float*)d_in[17];
  const float* wfc = (const float*)d_in[18];
  const float* pmlr= (const float*)d_in[19];
  const float* amlr= (const float*)d_in[20];
  float* ws = (float*)d_ws;
  float* mx      = ws;                             // 32768*384
  float* yn      = mx + (size_t)32768 * 384;       // 32768*4
  float* ubp     = yn + (size_t)32768 * 4;         // 32768*4
  float* bhi_f   = ubp + (size_t)32768 * 4;        // 147456 f32
  float* blo_f   = bhi_f + 147456;                 // 147456 f32
  float* uarr    = blo_f + 147456;                 // 256*128
  float* varr    = uarr + 256 * 128;               // 256*128
  uint4* Bh = (uint4*)bhi_f;
  uint4* Bl = (uint4*)blo_f;

  k_convB<<<dim3(144), dim3(256), 0, stream>>>(uz, ur, uh, Bh, Bl);
  k_gemm_fused<<<dim3(256), dim3(256), 0, stream>>>(seq, Bh, Bl, bz, br, bh,
                                                    mx, yn, ubp);
  k_scan<<<dim3(256), dim3(256), 0, stream>>>(mx, yn, ubp, wz, wr, wh,
                                              bz, br, bh, mask1, mask2,
                                              uarr, varr);
  k_final<<<dim3(256), dim3(64), 0, stream>>>(uarr, varr, wfu, wfv, bff, bffd,
                                              wfc, pmlr, amlr, cids, csemb,
                                              (float*)d_out);
}

// Round 13
// 502.844 us; speedup vs baseline: 1.0468x; 1.0468x over previous
//
#include <hip/hip_runtime.h>
#include <math.h>

#define MINN 1e-15f
#define ONE_EPS 0.99999f   // 1 - 1e-5 (artanh clamp)

__device__ __forceinline__ float clampart(float x) {
  return fminf(fmaxf(x, -1.0f + 1e-5f), 1.0f - 1e-5f);
}
__device__ __forceinline__ float redsum(float x) {
  #pragma unroll
  for (int m = 32; m; m >>= 1) x += __shfl_xor(x, m);
  return x;
}
// 5-level butterfly within each 32-lane half
__device__ __forceinline__ float redsum32(float x) {
  #pragma unroll
  for (int m = 16; m; m >>= 1) x += __shfl_xor(x, m);
  return x;
}
__device__ __forceinline__ float frcp(float x) { return __builtin_amdgcn_rcpf(x); }
__device__ __forceinline__ float frsq(float x) { return __builtin_amdgcn_rsqf(x); }
__device__ __forceinline__ float fexp2(float x) { return __builtin_amdgcn_exp2f(x); }
__device__ __forceinline__ float flog2(float x) { return __builtin_amdgcn_logf(x); }
__device__ __forceinline__ float ftanh(float x) {
  float e = fexp2(x * 2.88539008f);
  return 1.0f - 2.0f * frcp(e + 1.0f);
}
__device__ __forceinline__ float fatanh(float x) {
  return 0.34657359f * flog2((1.0f + x) * frcp(1.0f - x));
}
__device__ __forceinline__ float fsig(float x) {
  return frcp(1.0f + fexp2(-1.44269504f * x));
}
#define DOT4(a, b) ((a).x*(b).x + (a).y*(b).y + (a).z*(b).z + (a).w*(b).w)

// ---- bf16 split helpers (x = hi + lo, each bf16; rel err ~2^-18) ----------
__device__ __forceinline__ unsigned bfh(float x) {
  unsigned u = __float_as_uint(x);
  return (u + 0x7FFFu + ((u >> 16) & 1u)) >> 16;    // RNE to bf16 bits
}
__device__ __forceinline__ void splitpack(float4 q0, float4 q1,
                                          uint4& hi, uint4& lo) {
  unsigned h0=bfh(q0.x),h1=bfh(q0.y),h2=bfh(q0.z),h3=bfh(q0.w);
  unsigned h4=bfh(q1.x),h5=bfh(q1.y),h6=bfh(q1.z),h7=bfh(q1.w);
  float r0=q0.x-__uint_as_float(h0<<16), r1=q0.y-__uint_as_float(h1<<16);
  float r2=q0.z-__uint_as_float(h2<<16), r3=q0.w-__uint_as_float(h3<<16);
  float r4=q1.x-__uint_as_float(h4<<16), r5=q1.y-__uint_as_float(h5<<16);
  float r6=q1.z-__uint_as_float(h6<<16), r7=q1.w-__uint_as_float(h7<<16);
  hi = make_uint4(h0|(h1<<16), h2|(h3<<16), h4|(h5<<16), h6|(h7<<16));
  lo = make_uint4(bfh(r0)|(bfh(r1)<<16), bfh(r2)|(bfh(r3)<<16),
                  bfh(r4)|(bfh(r5)<<16), bfh(r6)|(bfh(r7)<<16));
}
typedef __attribute__((ext_vector_type(8))) short bf16x8;
typedef __attribute__((ext_vector_type(4))) float f32x4;
__device__ __forceinline__ bf16x8 asfrag(uint4 u) {
  union { uint4 u; bf16x8 f; } c; c.u = u; return c.f;
}

// -------- Kernel B0: U matrices -> bf16 hi/lo fragment-linear layout -------
__global__ __launch_bounds__(256) void k_convB(const float* __restrict__ uz,
    const float* __restrict__ ur, const float* __restrict__ uh,
    uint4* __restrict__ Bh, uint4* __restrict__ Bl) {
  int tid = threadIdx.x;
  int l = tid & 63;
  int s = blockIdx.x * 4 + (tid >> 6);     // 0..575
  int kt = s / 24, nt = s % 24;
  int n = nt * 16 + (l & 15);
  const float* U = (n < 128) ? uz : (n < 256 ? ur : uh);
  int i = n & 127;
  int k = kt * 32 + (l >> 4) * 8;
  float4 q0 = *reinterpret_cast<const float4*>(U + (size_t)i * 768 + k);
  float4 q1 = *reinterpret_cast<const float4*>(U + (size_t)i * 768 + k + 4);
  uint4 hi, lo;
  splitpack(q0, q1, hi, lo);
  Bh[(size_t)(kt * 24 + nt) * 64 + l] = hi;
  Bl[(size_t)(kt * 24 + nt) * 64 + l] = lo;
}

// -------- Kernel B: fused MFMA GEMM + expmap0 stats + mobius_matvec NL -----
// B staged per-kt in double-buffered LDS (48KB/buf): each B element enters
// the CU once (was 4x, one per wave) -> GEMM leaves the L2-delivery bound.
__global__ __launch_bounds__(256, 1) void k_gemm_fused(
    const float* __restrict__ A, const uint4* __restrict__ Bh,
    const uint4* __restrict__ Bl,
    const float* __restrict__ bzp, const float* __restrict__ brp,
    const float* __restrict__ bhp,
    float* __restrict__ mx, float* __restrict__ yn, float* __restrict__ ub) {
  __shared__ uint4 bstage[2][3072];        // [buf][Bh:0..1535 | Bl:1536..3071]
  int tid = threadIdx.x;
  int l = tid & 63;
  int wv = tid >> 6;                       // wave 0..3
  int wid = blockIdx.x * 4 + wv;           // 0..1023
  int mt0 = wid * 2;
  int mrow = l & 15;
  int koff = (l >> 4) * 8;
  int sbase = wv * 384 + l;                // staging slot base (6 chunks of 64)

  f32x4 acc[2][24];
  #pragma unroll
  for (int m = 0; m < 2; ++m)
    #pragma unroll
    for (int n = 0; n < 24; ++n) acc[m][n] = (f32x4){0.f, 0.f, 0.f, 0.f};
  float ssA0 = 0.f, ssA1 = 0.f;

  // prologue: stage kt=0 into buf 0
  {
    const uint4* sH = Bh;                  // kt=0
    const uint4* sL = Bl;
    #pragma unroll
    for (int j = 0; j < 6; ++j) {
      bstage[0][sbase + j * 64]        = sH[sbase + j * 64];
      bstage[0][1536 + sbase + j * 64] = sL[sbase + j * 64];
    }
  }
  __syncthreads();

  #pragma unroll 1
  for (int kt = 0; kt < 24; ++kt) {
    int cb = kt & 1;
    // stage kt+1 into the other buffer (loads overlap this kt's MFMA)
    if (kt + 1 < 24) {
      const uint4* sH = Bh + (size_t)(kt + 1) * 1536;
      const uint4* sL = Bl + (size_t)(kt + 1) * 1536;
      #pragma unroll
      for (int j = 0; j < 6; ++j) {
        bstage[cb ^ 1][sbase + j * 64]        = sH[sbase + j * 64];
        bstage[cb ^ 1][1536 + sbase + j * 64] = sL[sbase + j * 64];
      }
    }
    const float* a0p = A + (size_t)(mt0 * 16 + mrow) * 768 + kt * 32 + koff;
    const float* a1p = a0p + 16 * 768;
    float4 q0 = *reinterpret_cast<const float4*>(a0p);
    float4 q1 = *reinterpret_cast<const float4*>(a0p + 4);
    float4 q2 = *reinterpret_cast<const float4*>(a1p);
    float4 q3 = *reinterpret_cast<const float4*>(a1p + 4);
    ssA0 += DOT4(q0, q0) + DOT4(q1, q1);
    ssA1 += DOT4(q2, q2) + DOT4(q3, q3);
    uint4 ah0u, al0u, ah1u, al1u;
    splitpack(q0, q1, ah0u, al0u);
    splitpack(q2, q3, ah1u, al1u);
    bf16x8 ah0 = asfrag(ah0u), al0 = asfrag(al0u);
    bf16x8 ah1 = asfrag(ah1u), al1 = asfrag(al1u);
    const uint4* bhp4 = &bstage[cb][l];
    const uint4* blp4 = &bstage[cb][1536 + l];
    #pragma unroll
    for (int nt = 0; nt < 24; ++nt) {
      bf16x8 bh = asfrag(bhp4[nt * 64]);
      bf16x8 bl = asfrag(blp4[nt * 64]);
      acc[0][nt] = __builtin_amdgcn_mfma_f32_16x16x32_bf16(ah0, bh, acc[0][nt], 0, 0, 0);
      acc[0][nt] = __builtin_amdgcn_mfma_f32_16x16x32_bf16(ah0, bl, acc[0][nt], 0, 0, 0);
      acc[0][nt] = __builtin_amdgcn_mfma_f32_16x16x32_bf16(al0, bh, acc[0][nt], 0, 0, 0);
      acc[0][nt] = __builtin_amdgcn_mfma_f32_16x16x32_bf16(al0, bl, acc[0][nt], 0, 0, 0);
      acc[1][nt] = __builtin_amdgcn_mfma_f32_16x16x32_bf16(ah1, bh, acc[1][nt], 0, 0, 0);
      acc[1][nt] = __builtin_amdgcn_mfma_f32_16x16x32_bf16(ah1, bl, acc[1][nt], 0, 0, 0);
      acc[1][nt] = __builtin_amdgcn_mfma_f32_16x16x32_bf16(al1, bh, acc[1][nt], 0, 0, 0);
      acc[1][nt] = __builtin_amdgcn_mfma_f32_16x16x32_bf16(al1, bl, acc[1][nt], 0, 0, 0);
    }
    __syncthreads();   // staging complete + all waves done reading buf cb
  }
  // ---- seq row stats (A layout: lane covers koff-quarter of row mrow) ----
  ssA0 += __shfl_xor(ssA0, 16); ssA0 += __shfl_xor(ssA0, 32);
  ssA1 += __shfl_xor(ssA1, 16); ssA1 += __shfl_xor(ssA1, 32);
  float aA[2], rxA[2];
  {
    float un0 = sqrtf(ssA0), unc0 = fmaxf(un0, MINN);
    float a0 = tanhf(unc0) / unc0;
    float xn0 = fmaxf(a0 * un0, MINN);
    aA[0] = a0; rxA[0] = atanhf(clampart(xn0)) / xn0;
    float un1 = sqrtf(ssA1), unc1 = fmaxf(un1, MINN);
    float a1 = tanhf(unc1) / unc1;
    float xn1 = fmaxf(a1 * un1, MINN);
    aA[1] = a1; rxA[1] = atanhf(clampart(xn1)) / xn1;
  }
  // ---- remap stats to C-layout rows (row = r0 + j) ----
  int r0 = (l >> 4) * 4;
  float aC[2][4], rxC[2][4];
  #pragma unroll
  for (int m = 0; m < 2; ++m)
    #pragma unroll
    for (int j = 0; j < 4; ++j) {
      aC[m][j]  = __shfl(aA[m],  r0 + j);
      rxC[m][j] = __shfl(rxA[m], r0 + j);
    }
  // ---- bias values for ub dots: b_g[col], col = nt*16 + mrow ----
  float bv0[8], bv1[8], bv2[8];
  #pragma unroll
  for (int i = 0; i < 8; ++i) {
    bv0[i] = bzp[i * 16 + mrow];
    bv1[i] = brp[i * 16 + mrow];
    bv2[i] = bhp[i * 16 + mrow];
  }
#define GATE_EPI(m, g, bvarr)                                                 \
  {                                                                           \
    float ss0=0.f,ss1=0.f,ss2=0.f,ss3=0.f,sb0=0.f,sb1=0.f,sb2=0.f,sb3=0.f;    \
    _Pragma("unroll")                                                         \
    for (int ntg = 0; ntg < 8; ++ntg) {                                       \
      f32x4 v = acc[m][(g)*8 + ntg];                                          \
      float bb = bvarr[ntg];                                                  \
      ss0 += v[0]*v[0]; sb0 += v[0]*bb;                                       \
      ss1 += v[1]*v[1]; sb1 += v[1]*bb;                                       \
      ss2 += v[2]*v[2]; sb2 += v[2]*bb;                                       \
      ss3 += v[3]*v[3]; sb3 += v[3]*bb;                                       \
    }                                                                         \
    _Pragma("unroll")                                                         \
    for (int mk = 1; mk <= 8; mk <<= 1) {                                     \
      ss0 += __shfl_xor(ss0, mk); sb0 += __shfl_xor(sb0, mk);                 \
      ss1 += __shfl_xor(ss1, mk); sb1 += __shfl_xor(sb1, mk);                 \
      ss2 += __shfl_xor(ss2, mk); sb2 += __shfl_xor(sb2, mk);                 \
      ss3 += __shfl_xor(ss3, mk); sb3 += __shfl_xor(sb3, mk);                 \
    }                                                                         \
    float ssv[4] = {ss0, ss1, ss2, ss3};                                      \
    float sbv[4] = {sb0, sb1, sb2, sb3};                                      \
    float scale[4];                                                           \
    _Pragma("unroll")                                                         \
    for (int j = 0; j < 4; ++j) {                                             \
      float mxn = fmaxf(aC[m][j] * sqrtf(ssv[j]), MINN);                      \
      float tt = tanhf(mxn * rxC[m][j]);                                      \
      float sc = tt / mxn;                                                    \
      scale[j] = aC[m][j] * sc;                                               \
      if (mrow == 0) {                                                        \
        size_t row = (size_t)(mt0 + (m)) * 16 + r0 + j;                       \
        yn[row * 4 + (g)] = tt;                                               \
        ub[row * 4 + (g)] = scale[j] * sbv[j];                                \
      }                                                                       \
    }                                                                         \
    _Pragma("unroll")                                                         \
    for (int ntg = 0; ntg < 8; ++ntg) {                                       \
      int col = ((g)*8 + ntg) * 16 + mrow;                                    \
      f32x4 v = acc[m][(g)*8 + ntg];                                          \
      size_t rbase = (size_t)(mt0 + (m)) * 16 + r0;                           \
      _Pragma("unroll")                                                       \
      for (int j = 0; j < 4; ++j)                                             \
        mx[(rbase + j) * 384 + col] = v[j] * scale[j];                        \
    }                                                                         \
  }
  GATE_EPI(0, 0, bv0) GATE_EPI(0, 1, bv1) GATE_EPI(0, 2, bv2)
  GATE_EPI(1, 0, bv0) GATE_EPI(1, 1, bv1) GATE_EPI(1, 2, bv2)
#undef GATE_EPI
}

// ---------------- Kernel C: hyperbolic GRU scan, 4 waves per chain --------
// Weights in VGPRs; full input prefetch; rsq-folded chain; split-half
// reductions (A:3+3, B:4+3, C:1+1). hs/ps written by both halves
// (identical values; 2-way same-address LDS write is free).
__global__ __launch_bounds__(256, 1) void k_scan(
    const float* __restrict__ ux, const float* __restrict__ yn,
    const float* __restrict__ ub,
    const float* __restrict__ wz, const float* __restrict__ wr, const float* __restrict__ wh,
    const float* __restrict__ bzp, const float* __restrict__ brp, const float* __restrict__ bhp,
    const float* __restrict__ mask1, const float* __restrict__ mask2,
    float* __restrict__ uarr, float* __restrict__ varr) {
  __shared__ __align__(16) float hs[128];
  __shared__ __align__(16) float ps[128];
  __shared__ __align__(16) float part[72];
  float4* hs4   = (float4*)hs;
  float4* ps4   = (float4*)ps;
  float4* part4 = (float4*)part;

  int b = blockIdx.x;
  int tid = threadIdx.x;
  int w = tid >> 6;          // wave 0..3
  int l = tid & 63;          // lane
  int l31 = l & 31;
  int kh = l >> 5;           // k-half 0/1 (also reduction-subset selector)
  int o = w * 32 + l31;      // owned output/elem index

  const float4* wzg = (const float4*)wz;
  const float4* wrg = (const float4*)wr;
  const float4* whg = (const float4*)wh;
  float4 wzr[16], wrr[16], whr[16];
  #pragma unroll
  for (int i = 0; i < 16; ++i) {
    wzr[i] = wzg[o * 32 + kh * 16 + i];
    wrr[i] = wrg[o * 32 + kh * 16 + i];
    whr[i] = whg[o * 32 + kh * 16 + i];
  }

  float bzv = bzp[o], brv = brp[o], bhv = bhp[o];
  {
    float v0 = redsum32(bzv * bzv);
    float v1 = redsum32(brv * brv);
    float v2 = redsum32(bhv * bhv);
    if (l == 0) { part[15*4 + w] = v0; part[16*4 + w] = v1; part[17*4 + w] = v2; }
  }
  __syncthreads();
  float b2z, b2r, b2h;
  { float4 q;
    q = part4[15]; b2z = q.x + q.y + q.z + q.w;
    q = part4[16]; b2r = q.x + q.y + q.z + q.w;
    q = part4[17]; b2h = q.x + q.y + q.z + q.w; }

  float h = 0.f, hn2 = 0.f, au = 0.f, av = 0.f;
  const float*  uxb  = ux + (size_t)b * 128 * 384;
  const float4* ynb4 = (const float4*)yn + (size_t)b * 128;
  const float4* ubb4 = (const float4*)ub + (size_t)b * 128;
  const float*  m1p  = mask1 + b * 128;
  const float*  m2p  = mask2 + b * 128;

  // prefetch t=0 inputs
  float cuz = uxb[o], cur = uxb[128 + o], cuh = uxb[256 + o];
  float4 cyn = ynb4[0];
  float4 cub = ubb4[0];
  float cm1 = m1p[0], cm2 = m2p[0];

  #pragma unroll 1
  for (int t = 0; t < 128; ++t) {
    hs[o] = h;                            // both halves write identical value
    __syncthreads();                      // (1) h visible
    // issue ALL t+1 prefetches
    int tn = (t < 127) ? t + 1 : 127;
    const float* uxn = uxb + tn * 384;
    float nuz = uxn[o], nur = uxn[128 + o], nuh = uxn[256 + o];
    float4 nyn = ynb4[tn];
    float4 nub = ubb4[tn];
    float nm1 = m1p[tn], nm2 = m2p[tn];
    float uz = cuz, ur = cur, uh = cuh;
    float ynz = cyn.x, ynr = cyn.y, ynh = cyn.z;
    float ubz = cub.x, ubr = cub.y, ubh = cub.z;
    float m1 = cm1, m2 = cm2;

    // wave-uniform pre-chain
    float rqh  = frsq(fmaxf(hn2, 1e-30f));
    float xnh  = fmaxf(hn2, 1e-30f) * rqh;
    float arth = fatanh(fminf(xnh, ONE_EPS));
    float axr  = arth * rqh;

    // ---- z/r matvec: register weights x LDS-broadcast h ----
    float mzp = 0.f, mrp = 0.f;
    #pragma unroll
    for (int i = 0; i < 16; ++i) {
      float4 hv = hs4[kh * 16 + i];
      mzp += DOT4(wzr[i], hv);
      mrp += DOT4(wrr[i], hv);
    }
    float mz = mzp + __shfl_xor(mzp, 32);
    float mr = mrp + __shfl_xor(mrp, 32);

    // ---- window A: 6 reductions, split 3/3 across halves ----
    {
      float v0 = kh ? mr * mr  : mz * mz;
      float v1 = kh ? mr * ur  : mz * uz;
      float v2 = kh ? mr * brv : mz * bzv;
      v0 = redsum32(v0); v1 = redsum32(v1); v2 = redsum32(v2);
      if (l31 == 0) {
        int base = kh * 3;
        part[(base + 0) * 4 + w] = v0;
        part[(base + 1) * 4 + w] = v1;
        part[(base + 2) * 4 + w] = v2;
      }
    }
    __syncthreads();                      // (2) window A partials
    float sMz2, sMzUz, sMzBz, sMr2, sMrUr, sMrBr;
    { float4 q;
      q = part4[0]; sMz2  = q.x + q.y + q.z + q.w;
      q = part4[1]; sMzUz = q.x + q.y + q.z + q.w;
      q = part4[2]; sMzBz = q.x + q.y + q.z + q.w;
      q = part4[3]; sMr2  = q.x + q.y + q.z + q.w;
      q = part4[4]; sMrUr = q.x + q.y + q.z + q.w;
      q = part4[5]; sMrBr = q.x + q.y + q.z + q.w; }

    // ---- z chain (rsq-folded) ----
    float rqz = frsq(fmaxf(sMz2, 1e-30f));
    float mzn = fmaxf(sMz2, 1e-30f) * rqz;
    float tz  = ftanh(mzn * axr);
    float szs = tz * rqz;
    float xyz = szs * sMzUz;
    float y2z = ynz * ynz, x2z = tz * tz;
    float c1z = 1.f + 2.f * xyz + y2z, c2z = 1.f - x2z;
    float idnz = frcp(fmaxf(1.f + 2.f * xyz + x2z * y2z, MINN));
    float az  = (c1z * szs * mz + c2z * uz) * idnz;
    float az2 = fmaxf(idnz * idnz * (c1z * c1z * x2z + 2.f * c1z * c2z * xyz + c2z * c2z * y2z), 0.f);
    float azb = idnz * (c1z * szs * sMzBz + c2z * ubz);
    float c1zb = 1.f + 2.f * azb + b2z, c2zb = 1.f - az2;
    float idnzb = frcp(fmaxf(1.f + 2.f * azb + az2 * b2z, MINN));
    float cz = (c1zb * az + c2zb * bzv) * idnzb;
    float cn2z = fmaxf(idnzb * idnzb * (c1zb * c1zb * az2 + 2.f * c1zb * c2zb * azb + c2zb * c2zb * b2z), 0.f);
    float rqcz = frsq(fmaxf(cn2z, 1e-30f));
    float cnz = fmaxf(cn2z, 1e-30f) * rqcz;
    float lsz = fatanh(fminf(cnz, ONE_EPS)) * rqcz;
    float zg = fsig(lsz * cz);

    // ---- r chain ----
    float rqr = frsq(fmaxf(sMr2, 1e-30f));
    float mrn = fmaxf(sMr2, 1e-30f) * rqr;
    float trr = ftanh(mrn * axr);
    float srs = trr * rqr;
    float xyr = srs * sMrUr;
    float y2r = ynr * ynr, x2r = trr * trr;
    float c1r = 1.f + 2.f * xyr + y2r, c2r = 1.f - x2r;
    float idnr = frcp(fmaxf(1.f + 2.f * xyr + x2r * y2r, MINN));
    float ar  = (c1r * srs * mr + c2r * ur) * idnr;
    float ar2 = fmaxf(idnr * idnr * (c1r * c1r * x2r + 2.f * c1r * c2r * xyr + c2r * c2r * y2r), 0.f);
    float arb = idnr * (c1r * srs * sMrBr + c2r * ubr);
    float c1rb = 1.f + 2.f * arb + b2r, c2rb = 1.f - ar2;
    float idnrb = frcp(fmaxf(1.f + 2.f * arb + ar2 * b2r, MINN));
    float cr = (c1rb * ar + c2rb * brv) * idnrb;
    float cn2r = fmaxf(idnrb * idnrb * (c1rb * c1rb * ar2 + 2.f * c1rb * c2rb * arb + c2rb * c2rb * b2r), 0.f);
    float rqcr = frsq(fmaxf(cn2r, 1e-30f));
    float cnr = fmaxf(cn2r, 1e-30f) * rqcr;
    float lsr = fatanh(fminf(cnr, ONE_EPS)) * rqcr;
    float rg = fsig(lsr * cr);

    // ---- rh = h o r (unscaled p) ----
    float p = h * rg;
    ps[o] = p;                            // both halves, identical value
    __syncthreads();                      // (3) p visible

    // ---- h matvec from regs x ps broadcast ----
    float mhp = 0.f;
    #pragma unroll
    for (int i = 0; i < 16; ++i) {
      float4 pv = ps4[kh * 16 + i];
      mhp += DOT4(whr[i], pv);
    }
    float mh = mhp + __shfl_xor(mhp, 32);

    // ---- window B: 7 reductions, split 4/3 across halves ----
    {
      float v0 = kh ? (h * mh)  : (p * p);
      float v1 = kh ? (h * uh)  : (mh * mh);
      float v2 = kh ? (h * bhv) : (mh * uh);
      float v3 = kh ? 0.f       : (mh * bhv);
      v0 = redsum32(v0); v1 = redsum32(v1); v2 = redsum32(v2); v3 = redsum32(v3);
      if (l31 == 0) {
        if (kh) {
          part[10*4 + w] = v0; part[11*4 + w] = v1; part[12*4 + w] = v2;
        } else {
          part[6*4 + w] = v0; part[7*4 + w] = v1;
          part[8*4 + w] = v2; part[9*4 + w] = v3;
        }
      }
    }
    __syncthreads();                      // (4) window B partials
    float pn2, sMh2r, sMhUhr, sMhBhr, sHMhr, sHUh, sHBh;
    { float4 q;
      q = part4[6];  pn2    = q.x + q.y + q.z + q.w;
      q = part4[7];  sMh2r  = q.x + q.y + q.z + q.w;
      q = part4[8];  sMhUhr = q.x + q.y + q.z + q.w;
      q = part4[9];  sMhBhr = q.x + q.y + q.z + q.w;
      q = part4[10]; sHMhr  = q.x + q.y + q.z + q.w;
      q = part4[11]; sHUh   = q.x + q.y + q.z + q.w;
      q = part4[12]; sHBh   = q.x + q.y + q.z + q.w; }

    // ---- rh scaling + h~ chain (rsq-folded, srt folded) ----
    float rqp = frsq(fmaxf(pn2, 1e-30f));
    float pn  = fmaxf(pn2, 1e-30f) * rqp;
    float trh = ftanh(pn * axr);
    float srt = trh * rqp;
    float xnp  = fmaxf(trh, MINN);
    float artp = fatanh(fminf(xnp, ONE_EPS));
    float sqh  = fmaxf(sMh2r, 1e-30f) * frsq(fmaxf(sMh2r, 1e-30f));  // sqrt
    float mhn  = fmaxf(srt * sqh, MINN);
    float th   = ftanh(mhn * artp * frcp(xnp));
    float g    = th * frcp(mhn) * srt;
    float xyh  = g * sMhUhr;
    float y2h = ynh * ynh, x2h = th * th;
    float c1h = 1.f + 2.f * xyh + y2h, c2h = 1.f - x2h;
    float idnh = frcp(fmaxf(1.f + 2.f * xyh + x2h * y2h, MINN));
    float ah  = (c1h * g * mh + c2h * uh) * idnh;
    float ah2 = fmaxf(idnh * idnh * (c1h * c1h * x2h + 2.f * c1h * c2h * xyh + c2h * c2h * y2h), 0.f);
    float ahb = idnh * (c1h * g * sMhBhr + c2h * ubh);
    float hah = idnh * (c1h * g * sHMhr + c2h * sHUh);
    float c1hb = 1.f + 2.f * ahb + b2h, c2hb = 1.f - ah2;
    float idnhb = frcp(fmaxf(1.f + 2.f * ahb + ah2 * b2h, MINN));
    float ct  = (c1hb * ah + c2hb * bhv) * idnhb;
    float ct2 = fmaxf(idnhb * idnhb * (c1hb * c1hb * ah2 + 2.f * c1hb * c2hb * ahb + c2hb * c2hb * b2h), 0.f);
    float hct = idnhb * (c1hb * hah + c2hb * sHBh);

    // ---- delta = mobius_add(-h, h_tilde) ----
    float c1d = 1.f - 2.f * hct + ct2, c2d = 1.f - hn2;
    float idnd = frcp(fmaxf(1.f - 2.f * hct + hn2 * ct2, MINN));
    float dl = (c2d * ct - c1d * h) * idnd;
    float dn2 = fmaxf(idnd * idnd * (c1d * c1d * hn2 - 2.f * c1d * c2d * hct + c2d * c2d * ct2), 0.f);
    float wv = dl * zg;

    // ---- window C: 2 reductions, split 1/1 across halves ----
    {
      float vC = kh ? (h * wv) : (wv * wv);
      vC = redsum32(vC);
      if (l31 == 0) part[(13 + kh) * 4 + w] = vC;
    }
    __syncthreads();                      // (5) window C partials
    float wn2, hw;
    { float4 q;
      q = part4[13]; wn2 = q.x + q.y + q.z + q.w;
      q = part4[14]; hw  = q.x + q.y + q.z + q.w; }

    float rqd = frsq(fmaxf(dn2, 1e-30f));
    float dnv = fmaxf(dn2, 1e-30f) * rqd;
    float rqw = frsq(fmaxf(wn2, 1e-30f));
    float wnv = fmaxf(wn2, 1e-30f) * rqw;
    float tdd = ftanh(wnv * rqd * fatanh(fminf(dnv, ONE_EPS)));
    float szd = tdd * rqw;
    float zd = wv * szd;
    float hzd = hw * szd;
    float t2v = tdd * tdd;
    float c1f = 1.f + 2.f * hzd + t2v, c2f = 1.f - hn2;
    float idnf = frcp(fmaxf(1.f + 2.f * hzd + hn2 * t2v, MINN));
    float nh = (c1f * h + c2f * zd) * idnf;
    hn2 = fmaxf(idnf * idnf * (c1f * c1f * hn2 + 2.f * c1f * c2f * hzd + c2f * c2f * t2v), 0.f);
    h = nh;
    au += m1 * h; av += m2 * h;
    cuz = nuz; cur = nur; cuh = nuh;
    cyn = nyn; cub = nub; cm1 = nm1; cm2 = nm2;
  }
  if (l < 32) {
    uarr[b * 128 + o] = au;
    varr[b * 128 + o] = av;
  }
}

// ---------------- Kernel D: dist + mobius FF + hyperbolic MLR, 1 wave/b ----
__global__ __launch_bounds__(64) void k_final(
    const float* __restrict__ uarr, const float* __restrict__ varr,
    const float* __restrict__ wfu, const float* __restrict__ wfv,
    const float* __restrict__ bff, const float* __restrict__ bffd,
    const float* __restrict__ wfc, const float* __restrict__ pmlr,
    const float* __restrict__ amlr, const int* __restrict__ cids,
    const float* __restrict__ csemb, float* __restrict__ out) {
  int b = blockIdx.x;
  int l = threadIdx.x;
  __shared__ float us[128], vs[128], cbuf[64];
  float q0 = uarr[b * 128 + l], q1 = uarr[b * 128 + 64 + l];
  float r0 = varr[b * 128 + l], r1 = varr[b * 128 + 64 + l];
  us[l] = q0; us[l + 64] = q1; vs[l] = r0; vs[l + 64] = r1;
  __syncthreads();
  float u2 = redsum(q0 * q0 + q1 * q1);
  float v2 = redsum(r0 * r0 + r1 * r1);
  float uv = redsum(q0 * r0 + q1 * r1);
  float dsq;
  { float x2 = u2, y2 = v2, xy = -uv;
    float c1 = 1.f + 2.f * xy + y2, c2 = 1.f - x2;
    float idn = 1.f / fmaxf(1.f + 2.f * xy + x2 * y2, MINN);
    float d0 = (c1 * (-q0) + c2 * r0) * idn, d1 = (c1 * (-q1) + c2 * r1) * idn;
    float dn2 = redsum(d0 * d0 + d1 * d1);
    dsq = 2.f * atanhf(clampart(sqrtf(dn2))); }
  float mxu = 0.f, mxv = 0.f;
  #pragma unroll 4
  for (int jc = 0; jc < 128; jc += 4) {
    float4 uu = *reinterpret_cast<const float4*>(&us[jc]);
    float4 vv = *reinterpret_cast<const float4*>(&vs[jc]);
    float4 wu4 = *reinterpret_cast<const float4*>(wfu + (size_t)l * 128 + jc);
    float4 wv4 = *reinterpret_cast<const float4*>(wfv + (size_t)l * 128 + jc);
    mxu += DOT4(wu4, uu); mxv += DOT4(wv4, vv);
  }
  float xnu = fmaxf(sqrtf(u2), MINN);
  float xnv = fmaxf(sqrtf(v2), MINN);
  float mun = fmaxf(sqrtf(redsum(mxu * mxu)), MINN);
  float mvn = fmaxf(sqrtf(redsum(mxv * mxv)), MINN);
  float tu = tanhf(mun / xnu * atanhf(clampart(xnu)));
  float tv = tanhf(mvn / xnv * atanhf(clampart(xnv)));
  float fu = mxu * (tu / mun), fv = mxv * (tv / mvn);
  float o1;
  { float x2 = tu * tu, y2 = tv * tv, xy = redsum(fu * fv);
    float c1 = 1.f + 2.f * xy + y2, c2 = 1.f - x2;
    float idn = 1.f / fmaxf(1.f + 2.f * xy + x2 * y2, MINN);
    o1 = (c1 * fu + c2 * fv) * idn; }
  float bffl = bff[l];
  float bf2 = redsum(bffl * bffl);
  float o2;
  { float x2 = redsum(o1 * o1), y2 = bf2, xy = redsum(o1 * bffl);
    float c1 = 1.f + 2.f * xy + y2, c2 = 1.f - x2;
    float idn = 1.f / fmaxf(1.f + 2.f * xy + x2 * y2, MINN);
    o2 = (c1 * o1 + c2 * bffl) * idn; }
  float bdl = bffd[l];
  float bdn = fmaxf(sqrtf(redsum(bdl * bdl)), MINN);
  float tsm = tanhf(dsq * atanhf(clampart(bdn)));
  float sm = bdl * (tsm / bdn);
  float o3;
  { float x2 = redsum(o2 * o2), y2 = tsm * tsm, xy = redsum(o2 * sm);
    float c1 = 1.f + 2.f * xy + y2, c2 = 1.f - x2;
    float idn = 1.f / fmaxf(1.f + 2.f * xy + x2 * y2, MINN);
    o3 = (c1 * o2 + c2 * sm) * idn; }
  int cid = cids[b];
  float ce = csemb[(size_t)cid * 64 + l];
  cbuf[l] = ce;
  __syncthreads();
  float ce2 = redsum(ce * ce);
  float mxc = 0.f;
  #pragma unroll 4
  for (int jc = 0; jc < 64; jc += 4) {
    float4 cc = *reinterpret_cast<const float4*>(&cbuf[jc]);
    float4 wc4 = *reinterpret_cast<const float4*>(wfc + (size_t)l * 64 + jc);
    mxc += DOT4(wc4, cc);
  }
  float xnc = fmaxf(sqrtf(ce2), MINN);
  float mcn = fmaxf(sqrtf(redsum(mxc * mxc)), MINN);
  float tc = tanhf(mcn / xnc * atanhf(clampart(xnc)));
  float fc = mxc * (tc / mcn);
  float o4;
  { float x2 = redsum(o3 * o3), y2 = tc * tc, xy = redsum(o3 * fc);
    float c1 = 1.f + 2.f * xy + y2, c2 = 1.f - x2;
    float idn = 1.f / fmaxf(1.f + 2.f * xy + x2 * y2, MINN);
    o4 = (c1 * o3 + c2 * fc) * idn; }
  float on = fmaxf(sqrtf(redsum(o4 * o4)), MINN);
  float lo = o4 * (atanhf(clampart(on)) / on);
  float un = fmaxf(sqrtf(redsum(lo * lo)), MINN);
  float eo = lo * (tanhf(un) / un);
  float eo2 = redsum(eo * eo);
  for (int c = 0; c < 4; ++c) {
    float pc = pmlr[c * 64 + l];
    float ac = amlr[c * 64 + l];
    float p2 = redsum(pc * pc);
    float pe = redsum(pc * eo);
    float x2 = p2, y2 = eo2, xy = -pe;
    float c1 = 1.f + 2.f * xy + y2, c2 = 1.f - x2;
    float idn = 1.f / fmaxf(1.f + 2.f * xy + x2 * y2, MINN);
    float mp = (c1 * (-pc) + c2 * eo) * idn;
    float mp2 = redsum(mp * mp);
    float lam = 2.f / (1.f - mp2);
    float na = sqrtf(redsum(ac * ac));
    float au = ac / fmaxf(na, 1e-12f);
    float pda = redsum(mp * au);
    if (l == 0) out[b * 4 + c] = 2.f * na * asinhf(pda * lam);
  }
}

extern "C" void kernel_launch(void* const* d_in, const int* in_sizes, int n_in,
                              void* d_out, int out_size, void* d_ws, size_t ws_size,
                              hipStream_t stream) {
  const float* seq   = (const float*)d_in[0];
  const float* mask1 = (const float*)d_in[1];
  const float* mask2 = (const float*)d_in[2];
  const int*   cids  = (const int*)d_in[3];
  const float* csemb = (const float*)d_in[4];
  const float* wz  = (const float*)d_in[5];
  const float* wr  = (const float*)d_in[6];
  const float* wh  = (const float*)d_in[7];
  const float* uz  = (const float*)d_in[8];
  const float* ur  = (const float*)d_in[9];
  const float* uh  = (const float*)d_in[10];
  const float* bz  = (const float*)d_in[11];
  const float* br  = (const float*)d_in[12];
  const float* bh  = (const float*)d_in[13];
  const float* wfu = (const float*)d_in[14];
  const float* wfv = (const float*)d_in[15];
  const float* bff = (const float*)d_in[16];
  const float* bffd= (const float*)d_in[17];
  const float* wfc = (const float*)d_in[18];
  const float* pmlr= (const float*)d_in[19];
  const float* amlr= (const float*)d_in[20];
  float* ws = (float*)d_ws;
  float* mx      = ws;                             // 32768*384
  float* yn      = mx + (size_t)32768 * 384;       // 32768*4
  float* ubp     = yn + (size_t)32768 * 4;         // 32768*4
  float* bhi_f   = ubp + (size_t)32768 * 4;        // 147456 f32
  float* blo_f   = bhi_f + 147456;                 // 147456 f32
  float* uarr    = blo_f + 147456;                 // 256*128
  float* varr    = uarr + 256 * 128;               // 256*128
  uint4* Bh = (uint4*)bhi_f;
  uint4* Bl = (uint4*)blo_f;

  k_convB<<<dim3(144), dim3(256), 0, stream>>>(uz, ur, uh, Bh, Bl);
  k_gemm_fused<<<dim3(256), dim3(256), 0, stream>>>(seq, Bh, Bl, bz, br, bh,
                                                    mx, yn, ubp);
  k_scan<<<dim3(256), dim3(256), 0, stream>>>(mx, yn, ubp, wz, wr, wh,
                                              bz, br, bh, mask1, mask2,
                                              uarr, varr);
  k_final<<<dim3(256), dim3(64), 0, stream>>>(uarr, varr, wfu, wfv, bff, bffd,
                                              wfc, pmlr, amlr, cids, csemb,
                                              (float*)d_out);
}